// Round 29
// baseline (580.204 us; speedup 1.0000x reference)
//
#include <hip/hip_runtime.h>

typedef __attribute__((ext_vector_type(8))) short bf16x8;
typedef __attribute__((ext_vector_type(4))) float f32x4;

// Bijective XCD-aware block swizzle (m204 variant; safe for nwg % 8 != 0).
__device__ __forceinline__ int xcd_swizzle(int bid, int nwg) {
    int q = nwg >> 3, r = nwg & 7;
    int xcd = bid & 7, idx = bid >> 3;
    return (xcd < r) ? xcd * (q + 1) + idx
                     : r * (q + 1) + (xcd - r) * q + idx;
}

// split fp32 -> bf16 hi + bf16 lo  (hi = truncated top16; lo = bf16(f - hi))
__device__ __forceinline__ void split_bf16(const float* v, bf16x8& hi, bf16x8& lo) {
    #pragma unroll
    for (int j = 0; j < 8; ++j) {
        unsigned u = __float_as_uint(v[j]);
        unsigned h = u >> 16;
        hi[j] = (short)h;
        float hf = __uint_as_float(h << 16);
        float lf = v[j] - hf;
        lo[j] = (short)(__float_as_uint(lf) >> 16);
    }
}

// ---------------------------------------------------------------------------
// Stage 1 v2b: conv1 (11x11) + ReLU + maxpool. Output row stride 72 (padded).
// ---------------------------------------------------------------------------
__global__ __launch_bounds__(256, 4) void conv1_pool_v2_kernel(
    const float* __restrict__ x, const float* __restrict__ w,
    const float* __restrict__ bias, float* __restrict__ out)
{
    const int tile = blockIdx.x;          // 0..24
    const int cog  = blockIdx.y;          // 0..3  (8 couts each)
    const int b    = blockIdx.z;          // 0..31
    const int ty = tile / 5, tx = tile % 5;
    const int pr0 = ty * 16, pc0 = tx * 16;
    const int cr0 = pr0 * 2, cc0 = pc0 * 2;

    __shared__ float in_s[43 * 44];
    __shared__ float w_s[8][121];
    __shared__ float hp_s[33][8][17];

    const int tid = threadIdx.x;

    const float* xb = x + b * 152 * 152;
    for (int i = tid; i < 43 * 44; i += 256) {
        int r = i / 44, c = i - r * 44;
        int ir = cr0 + r, ic = cc0 + c;
        in_s[i] = (ir < 152 && ic < 152) ? xb[ir * 152 + ic] : 0.f;
    }
    for (int i = tid; i < 8 * 121; i += 256) {
        int co = i / 121, k = i - co * 121;
        w_s[co][k] = w[(cog * 8 + co) * 121 + k];
    }
    __syncthreads();

    for (int task = tid; task < 264; task += 256) {
        const int co  = task & 7;
        const int row = task >> 3;
        float hmax[16];
        if (cr0 + row < 142) {
            float acc[33];
            #pragma unroll
            for (int px = 0; px < 33; ++px) acc[px] = 0.f;
            #pragma unroll 1
            for (int kh = 0; kh < 11; ++kh) {
                float4 rq[11];
                #pragma unroll
                for (int j = 0; j < 11; ++j)
                    rq[j] = *reinterpret_cast<const float4*>(
                        &in_s[(row + kh) * 44 + j * 4]);
                const float* rr = reinterpret_cast<const float*>(rq);
                #pragma unroll
                for (int kw = 0; kw < 11; ++kw) {
                    float wv = w_s[co][kh * 11 + kw];
                    #pragma unroll
                    for (int px = 0; px < 33; ++px)
                        acc[px] += rr[px + kw] * wv;
                }
            }
            const float bv = bias[cog * 8 + co];
            #pragma unroll
            for (int px = 0; px < 33; ++px) {
                float v = fmaxf(acc[px] + bv, 0.f);
                acc[px] = (cc0 + px < 142) ? v : 0.f;
            }
            #pragma unroll
            for (int pc = 0; pc < 16; ++pc)
                hmax[pc] = fmaxf(fmaxf(acc[2 * pc], acc[2 * pc + 1]), acc[2 * pc + 2]);
        } else {
            #pragma unroll
            for (int pc = 0; pc < 16; ++pc) hmax[pc] = 0.f;
        }
        #pragma unroll
        for (int pc = 0; pc < 16; ++pc) hp_s[row][co][pc] = hmax[pc];
    }
    __syncthreads();

    for (int t = tid; t < 2048; t += 256) {
        int co = t >> 8, r = t & 255;
        int ppy = r >> 4, ppc = r & 15;
        float v = fmaxf(fmaxf(hp_s[2 * ppy][co][ppc], hp_s[2 * ppy + 1][co][ppc]),
                        hp_s[2 * ppy + 2][co][ppc]);
        int pr = pr0 + ppy, pc = pc0 + ppc;
        if (pr < 71 && pc < 71)
            out[((b * 32 + cog * 8 + co) * 71 + pr) * 72 + pc] = v;
    }
}

// ---------------------------------------------------------------------------
// conv2 weight prepass: fp32 [16co][32ci][9][9] -> bf16 hi/lo in
// k-order (khkw, ci): dst[khkw*512 + co*32 + ci].
// ---------------------------------------------------------------------------
__global__ __launch_bounds__(256) void conv2_wprep_kernel(
    const float* __restrict__ w, unsigned short* __restrict__ wh,
    unsigned short* __restrict__ wl)
{
    int i = blockIdx.x * 256 + threadIdx.x;
    if (i >= 41472) return;
    int ci = i & 31, co = (i >> 5) & 15, khkw = i >> 9;
    float v = w[(co * 32 + ci) * 81 + khkw];
    unsigned u = __float_as_uint(v);
    unsigned h = u >> 16;
    wh[i] = (unsigned short)h;
    float lf = v - __uint_as_float(h << 16);
    wl[i] = (unsigned short)(__float_as_uint(lf) >> 16);
}

// ---------------------------------------------------------------------------
// Stage 2 v6 (MFMA): conv2 + ReLU, bf16x3. (round-23 version, unchanged)
// ---------------------------------------------------------------------------
__global__ __launch_bounds__(256) void conv2_mfma_kernel(
    const float* __restrict__ in, const unsigned short* __restrict__ wh,
    const unsigned short* __restrict__ wl, const float* __restrict__ bias,
    float* __restrict__ out)
{
    __shared__ unsigned short inh[12 * 24 * 32];
    __shared__ unsigned short inl[12 * 24 * 32];

    const int owt = blockIdx.x;            // 0..3
    const int ohg = blockIdx.y;            // 0..15
    const int b   = blockIdx.z;            // 0..31
    const int ow0 = owt * 16, r0 = ohg * 4;
    const int tid = threadIdx.x;

    for (int t = tid; t < 384; t += 256) {
        int r = t >> 5, ci = t & 31;
        int ih = r0 + r;
        const bool rowok = (ih < 71);
        const float* src = in + ((size_t)(b * 32 + ci) * 71 + ih) * 72 + ow0;
        float4 f[6];
        #pragma unroll
        for (int c4 = 0; c4 < 6; ++c4)
            f[c4] = *reinterpret_cast<const float4*>(src + c4 * 4);  // safe: ws
        const float* vals = reinterpret_cast<const float*>(f);
        unsigned short* ph = &inh[(r * 24) * 32 + ci];
        unsigned short* pl = &inl[(r * 24) * 32 + ci];
        #pragma unroll
        for (int c = 0; c < 24; ++c) {
            float v = (rowok && (ow0 + c) < 71) ? vals[c] : 0.f;
            unsigned u = __float_as_uint(v);
            unsigned h = u >> 16;
            ph[c * 32] = (unsigned short)h;
            float lf = v - __uint_as_float(h << 16);
            pl[c * 32] = (unsigned short)(__float_as_uint(lf) >> 16);
        }
    }
    __syncthreads();

    const int wid  = tid >> 6;
    const int lane = tid & 63;
    const int q15  = lane & 15;
    const int kq   = lane >> 4;
    const int oh   = r0 + wid;

    f32x4 acc = {0.f, 0.f, 0.f, 0.f};

    #pragma unroll 1
    for (int kh = 0; kh < 9; ++kh) {
        #pragma unroll
        for (int kw = 0; kw < 9; ++kw) {
            const int s = kh * 9 + kw;
            const int abase = ((wid + kh) * 24 + (q15 + kw)) * 32 + kq * 8;
            bf16x8 ah = *reinterpret_cast<const bf16x8*>(&inh[abase]);
            bf16x8 al = *reinterpret_cast<const bf16x8*>(&inl[abase]);
            const int bbase = (s * 16 + q15) * 32 + kq * 8;
            bf16x8 bh = *reinterpret_cast<const bf16x8*>(&wh[bbase]);
            bf16x8 bl = *reinterpret_cast<const bf16x8*>(&wl[bbase]);
            acc = __builtin_amdgcn_mfma_f32_16x16x32_bf16(ah, bh, acc, 0, 0, 0);
            acc = __builtin_amdgcn_mfma_f32_16x16x32_bf16(ah, bl, acc, 0, 0, 0);
            acc = __builtin_amdgcn_mfma_f32_16x16x32_bf16(al, bh, acc, 0, 0, 0);
        }
    }

    if (oh < 63) {
        const int co = q15;
        const int pw = kq * 4;
        const float bv = bias[co];
        float r4[4];
        #pragma unroll
        for (int j = 0; j < 4; ++j) r4[j] = fmaxf(acc[j] + bv, 0.f);
        float* dst = &out[((size_t)(b * 16 + co) * 63 + oh) * 64 + ow0 + pw];
        if (ow0 + pw + 3 < 63) {
            *reinterpret_cast<float4*>(dst) = make_float4(r4[0], r4[1], r4[2], r4[3]);
        } else {
            #pragma unroll
            for (int j = 0; j < 4; ++j)
                if (ow0 + pw + j < 63) dst[j] = r4[j];
        }
    }
}

// ---------------------------------------------------------------------------
// Stage 3 (lc1) v19: MFMA bf16x3, 3-way split-K + LDS-STAGED WEIGHTS.
// v18's reg-direct weight loads put consecutive lanes 5184B apart -> each
// wave-load = 16 scattered 128B DRAM runs -> measured ~870 GB/s effective
// (the invariant 172-174us across all split-K/occupancy variants). v19
// stages the 16 x ~1.8KB CONTIGUOUS weight rows into LDS with coalesced
// float4 loads (1.8KB DRAM runs), then reads B-frags from LDS (same
// SPAN=452 bank rotation as A; conflict-free). LDS 2x28.9 + 8 = 66KB ->
// 2 blocks/CU x 8 waves. Register pipeline dropped: compute is all-LDS.
// ---------------------------------------------------------------------------
__global__ __launch_bounds__(512) void lc1_mfma_kernel(
    const float* __restrict__ in, const float* __restrict__ w,
    float* __restrict__ part)
{
    constexpr int K     = 1296;
    constexpr int WPAD  = 64;
    constexpr int PLANE = 63 * WPAD;       // 4032
    constexpr int CHW   = 16 * PLANE;      // 64512
    constexpr int HW    = 55 * 55;
    constexpr int SPAN  = 452;             // 452%32=4 -> bank-rotated rows

    __shared__ float patch_f[16 * SPAN];   // 28,928 B
    __shared__ float w_lds[16 * SPAN];     // 28,928 B
    __shared__ float red[8 * 256];         //  8,192 B

    const int tid = threadIdx.x;
    const int sb = xcd_swizzle(blockIdx.x, 6 * HW);
    const int pos  = sb / 6;
    const int rem  = sb - pos * 6;
    const int halfv = rem / 3;
    const int ks    = rem - halfv * 3;
    const int sbeg = (ks == 0) ? 0 : (ks == 1) ? 14 : 28;
    const int send = (ks == 0) ? 14 : (ks == 1) ? 28 : 41;
    const int klo  = sbeg * 32;            // 0 / 448 / 896
    const int spanUsed = send * 32 - klo;  // 448 / 448 / 416
    const int wreal = (ks == 2) ? 400 : spanUsed;   // real weight floats/row
    const int rbeg = klo / 9;              // 0 / 49 / 99
    const int rend = min((send * 32 - 1) / 9, 143);
    const int nrows = rend - rbeg + 1;

    const int oh = pos / 55, ow = pos % 55;
    const int sh = ow & 3;
    const int gbase = oh * WPAD + (ow - sh);

    // ks2: zero tail locals [400,416) in both tiles (never staged)
    if (ks == 2) {
        for (int i = tid; i < 16 * 16; i += 512) {
            patch_f[(i >> 4) * SPAN + 400 + (i & 15)] = 0.f;
            w_lds[(i >> 4) * SPAN + 400 + (i & 15)] = 0.f;
        }
    }

    // ---- stage WEIGHT k-slice: 16 rows x wreal floats, each row contiguous
    //      in memory -> coalesced float4 loads (1.8KB DRAM runs). ----
    {
        const float* wtile = w + (size_t)pos * 16 * K + klo;
        const int rowf4 = wreal >> 2;              // 112 / 112 / 100
        for (int i = tid; i < 16 * rowf4; i += 512) {
            const int co = i / rowf4, off4 = i - co * rowf4;
            float4 v = *reinterpret_cast<const float4*>(
                wtile + (size_t)co * K + off4 * 4);
            *reinterpret_cast<float4*>(&w_lds[co * SPAN + off4 * 4]) = v;
        }
    }

    // ---- stage patch rows (guarded per element) ----
    const float* inb = in + halfv * 16 * CHW;
    for (int t = tid; t < 16 * nrows; t += 512) {
        const int b    = t & 15;
        const int rest = rbeg + (t >> 4);
        const float* src = inb + b * CHW + (rest / 9) * PLANE
                         + gbase + (rest - (rest / 9) * 9) * WPAD;
        float4 f0 = *reinterpret_cast<const float4*>(src);
        float4 f1 = *reinterpret_cast<const float4*>(src + 4);
        float4 f2 = *reinterpret_cast<const float4*>(src + 8);
        float vals[12];
        *reinterpret_cast<float4*>(&vals[0]) = f0;
        *reinterpret_cast<float4*>(&vals[4]) = f1;
        *reinterpret_cast<float4*>(&vals[8]) = f2;
        float* p = &patch_f[b * SPAN];
        const int kbase = rest * 9;
        #pragma unroll
        for (int j = 0; j < 9; ++j) {
            const int local = kbase + j - klo;
            if (local >= 0 && local < spanUsed)
                p[local] = vals[sh + j];
        }
    }
    __syncthreads();

    // ---- MFMA compute over this block's ksteps (all operands in LDS) ----
    const int wid  = tid >> 6;             // wave 0..7
    const int lane = tid & 63;
    const int bq = lane & 15;              // A row (b) / B col (co)
    const int kq = lane >> 4;              // 0..3 -> k-run (kq*8)

    f32x4 acc = {0.f, 0.f, 0.f, 0.f};

    #pragma unroll 1
    for (int s = sbeg + wid; s < send; s += 8) {
        const int loc = (s * 32 - klo) + kq * 8;
        float av[8], wv[8];
        *reinterpret_cast<float4*>(&av[0]) =
            *reinterpret_cast<const float4*>(&patch_f[bq * SPAN + loc]);
        *reinterpret_cast<float4*>(&av[4]) =
            *reinterpret_cast<const float4*>(&patch_f[bq * SPAN + loc + 4]);
        *reinterpret_cast<float4*>(&wv[0]) =
            *reinterpret_cast<const float4*>(&w_lds[bq * SPAN + loc]);
        *reinterpret_cast<float4*>(&wv[4]) =
            *reinterpret_cast<const float4*>(&w_lds[bq * SPAN + loc + 4]);
        bf16x8 ah, al, bh, bl;
        split_bf16(av, ah, al);
        split_bf16(wv, bh, bl);
        acc = __builtin_amdgcn_mfma_f32_16x16x32_bf16(ah, bh, acc, 0, 0, 0);
        acc = __builtin_amdgcn_mfma_f32_16x16x32_bf16(ah, bl, acc, 0, 0, 0);
        acc = __builtin_amdgcn_mfma_f32_16x16x32_bf16(al, bh, acc, 0, 0, 0);
    }

    // ---- in-block reduce across 8 waves -> partial out ----
    *reinterpret_cast<float4*>(&red[(wid * 64 + lane) * 4]) =
        make_float4(acc[0], acc[1], acc[2], acc[3]);
    __syncthreads();

    if (tid < 256) {
        float s2 = 0.f;
        #pragma unroll
        for (int wv2 = 0; wv2 < 8; ++wv2)
            s2 += red[wv2 * 256 + tid];
        part[((size_t)(pos * 2 + halfv) * 3 + ks) * 256 + tid] = s2;
    }
}

// lc1 split-K reduce: sum 3 ksplits + bias + relu -> h3.
__global__ __launch_bounds__(256) void lc1_reduce_kernel(
    const float* __restrict__ part, const float* __restrict__ bias,
    float* __restrict__ out)
{
    constexpr int HW = 55 * 55;
    int idx = blockIdx.x * 256 + threadIdx.x;
    if (idx >= HW * 2 * 256) return;
    int base = idx >> 8;
    int t    = idx & 255;
    float v = part[((size_t)base * 3 + 0) * 256 + t]
            + part[((size_t)base * 3 + 1) * 256 + t]
            + part[((size_t)base * 3 + 2) * 256 + t];
    int pos = base >> 1, half = base & 1;
    int lane = t >> 2, reg = t & 3;
    int row = ((lane >> 4) << 2) + reg;
    int col = lane & 15;
    int b = half * 16 + row;
    out[(b * 16 + col) * HW + pos] = fmaxf(v + bias[col * HW + pos], 0.f);
}

// ---------------------------------------------------------------------------
// Stages 4-5 (lc2, lc3) v10: proven template, unchanged.
// ---------------------------------------------------------------------------
template<int KS, int STRIDE, int HIN, int WIN, int HOUT, int WOUT>
__global__ __launch_bounds__(512) void lc_v10_kernel(
    const float* __restrict__ in, const float* __restrict__ w,
    const float* __restrict__ bias, float* __restrict__ out)
{
    constexpr int K     = 16 * KS * KS;
    constexpr int K2    = KS * KS;
    constexpr int NPASS = (K + 127) / 128;
    constexpr int KPAD  = NPASS * 128;
    constexpr int HW    = HOUT * WOUT;
    constexpr int CHW   = 16 * HIN * WIN;

    __shared__ float patch_s[2][4096];
    __shared__ int   base_s[KPAD];

    const int tid = threadIdx.x;
    const int pos = xcd_swizzle(blockIdx.x, HW);
    const int oh = pos / WOUT, ow = pos % WOUT;
    const int posoff = (oh * STRIDE) * WIN + ow * STRIDE;

    for (int k = tid; k < KPAD; k += 512) {
        int v = 0;
        if (k < K) {
            int ci = k / K2;
            int r  = k - ci * K2;
            int kh = r / KS, kw = r - kh * KS;
            v = ci * (HIN * WIN) + kh * WIN + kw;
        }
        base_s[k] = v;
    }

    const int kl  = tid & 31;
    const int cog = (tid >> 5) & 3;
    const int bg  = tid >> 7;
    const int b0  = bg * 8;

    const int sb = tid >> 5;
    const int k0 = (tid & 31) * 4;
    const float* gsrc0 = in + sb * CHW + posoff;
    const float* gsrc1 = gsrc0 + 16 * CHW;

    const float* wbase = w + (size_t)pos * 16 * K;

    float acc[8][4];
    #pragma unroll
    for (int i = 0; i < 8; ++i)
        #pragma unroll
        for (int j = 0; j < 4; ++j) acc[i][j] = 0.f;

    __syncthreads();

    {
        int4 off4 = *reinterpret_cast<const int4*>(&base_s[k0]);
        float t0x = gsrc0[off4.x], t0y = gsrc0[off4.y],
              t0z = gsrc0[off4.z], t0w = gsrc0[off4.w];
        float t1x = gsrc1[off4.x], t1y = gsrc1[off4.y],
              t1z = gsrc1[off4.z], t1w = gsrc1[off4.w];
        *reinterpret_cast<float4*>(&patch_s[0][tid * 4]) =
            make_float4(t0x, t0y, t0z, t0w);
        *reinterpret_cast<float4*>(&patch_s[0][2048 + tid * 4]) =
            make_float4(t1x, t1y, t1z, t1w);
    }
    asm volatile("s_waitcnt lgkmcnt(0)" ::: "memory");
    __builtin_amdgcn_s_barrier();

    int cur = 0;
    #pragma unroll 1
    for (int ps = 0; ps < NPASS; ++ps) {
        const bool more = (ps + 1 < NPASS);
        float4 wv[4];
        {
            const int kw4 = ps * 128 + kl * 4;
            #pragma unroll
            for (int cj = 0; cj < 4; ++cj)
                wv[cj] = (kw4 < K)
                    ? *reinterpret_cast<const float4*>(wbase + (size_t)(cog * 4 + cj) * K + kw4)
                    : make_float4(0.f, 0.f, 0.f, 0.f);
        }
        float t0x, t0y, t0z, t0w, t1x, t1y, t1z, t1w;
        if (more) {
            int4 off4 = *reinterpret_cast<const int4*>(&base_s[(ps + 1) * 128 + k0]);
            t0x = gsrc0[off4.x]; t0y = gsrc0[off4.y];
            t0z = gsrc0[off4.z]; t0w = gsrc0[off4.w];
            t1x = gsrc1[off4.x]; t1y = gsrc1[off4.y];
            t1z = gsrc1[off4.z]; t1w = gsrc1[off4.w];
        }
        #pragma unroll
        for (int bi = 0; bi < 8; ++bi) {
            float4 pv = *reinterpret_cast<const float4*>(
                &patch_s[cur][(b0 + bi) * 128 + kl * 4]);
            #pragma unroll
            for (int cj = 0; cj < 4; ++cj)
                acc[bi][cj] += pv.x * wv[cj].x + pv.y * wv[cj].y
                             + pv.z * wv[cj].z + pv.w * wv[cj].w;
        }
        if (more) {
            *reinterpret_cast<float4*>(&patch_s[cur ^ 1][tid * 4]) =
                make_float4(t0x, t0y, t0z, t0w);
            *reinterpret_cast<float4*>(&patch_s[cur ^ 1][2048 + tid * 4]) =
                make_float4(t1x, t1y, t1z, t1w);
        }
        asm volatile("s_waitcnt lgkmcnt(0)" ::: "memory");
        __builtin_amdgcn_s_barrier();
        cur ^= 1;
    }

    #pragma unroll
    for (int bi = 0; bi < 8; ++bi)
        #pragma unroll
        for (int cj = 0; cj < 4; ++cj) {
            float v = acc[bi][cj];
            v += __shfl_xor(v, 1);
            v += __shfl_xor(v, 2);
            v += __shfl_xor(v, 4);
            v += __shfl_xor(v, 8);
            v += __shfl_xor(v, 16);
            acc[bi][cj] = v;
        }

    if (kl == 0) {
        float bv[4];
        #pragma unroll
        for (int cj = 0; cj < 4; ++cj)
            bv[cj] = bias[(cog * 4 + cj) * HW + pos];
        #pragma unroll
        for (int bi = 0; bi < 8; ++bi)
            #pragma unroll
            for (int cj = 0; cj < 4; ++cj) {
                int b = b0 + bi, co = cog * 4 + cj;
                out[(b * 16 + co) * HW + pos] = fmaxf(acc[bi][cj] + bv[cj], 0.f);
            }
    }
}

// ---------------------------------------------------------------------------
// Stage 6 v5: FC (32,7056)@(4096,7056)^T, 4-way split-K (proven r25 config).
// ---------------------------------------------------------------------------
__global__ __launch_bounds__(512) void fc_v5_kernel(
    const float* __restrict__ in, const float* __restrict__ w,
    float* __restrict__ part)
{
    constexpr int K = 7056, KR = 1764;
    constexpr int NPASS = (KR + 127) / 128;   // 14

    __shared__ float patch_s[2][4096];

    const int tid  = threadIdx.x;
    const int oblk = blockIdx.x;
    const int ks   = blockIdx.y;
    const int kbeg = ks * KR, klim = kbeg + KR;

    const int kl  = tid & 31;
    const int cog = (tid >> 5) & 3;
    const int bg  = tid >> 7;
    const int b0  = bg * 8;

    const int sb = tid >> 5;
    const int k0 = (tid & 31) * 4;
    const float* row0 = in + sb * K;
    const float* row1 = row0 + 16 * K;

    const float* wbase = w + (size_t)(oblk * 16) * K;

    auto ld4 = [&](const float* row, int kg) -> float4 {
        return (kg < klim) ? *reinterpret_cast<const float4*>(row + kg)
                           : make_float4(0.f, 0.f, 0.f, 0.f);
    };

    float acc[8][4];
    #pragma unroll
    for (int i = 0; i < 8; ++i)
        #pragma unroll
        for (int j = 0; j < 4; ++j) acc[i][j] = 0.f;

    float4 wv[4], wvn[4];
    float4 t0, t1;

    {
        const int kw4 = kbeg + kl * 4;
        #pragma unroll
        for (int cj = 0; cj < 4; ++cj)
            wv[cj] = (kw4 < klim)
                ? *reinterpret_cast<const float4*>(wbase + (size_t)(cog * 4 + cj) * K + kw4)
                : make_float4(0.f, 0.f, 0.f, 0.f);
        t0 = ld4(row0, kbeg + k0);
        t1 = ld4(row1, kbeg + k0);
        *reinterpret_cast<float4*>(&patch_s[0][tid * 4]) = t0;
        *reinterpret_cast<float4*>(&patch_s[0][2048 + tid * 4]) = t1;
    }
    __syncthreads();

    int cur = 0;
    #pragma unroll 1
    for (int ps = 0; ps < NPASS; ++ps) {
        const bool more = (ps + 1 < NPASS);
        if (more) {
            const int kbn = kbeg + (ps + 1) * 128;
            t0 = ld4(row0, kbn + k0);
            t1 = ld4(row1, kbn + k0);
            const int kw4n = kbn + kl * 4;
            #pragma unroll
            for (int cj = 0; cj < 4; ++cj)
                wvn[cj] = (kw4n < klim)
                    ? *reinterpret_cast<const float4*>(wbase + (size_t)(cog * 4 + cj) * K + kw4n)
                    : make_float4(0.f, 0.f, 0.f, 0.f);
        }
        #pragma unroll
        for (int bi = 0; bi < 8; ++bi) {
            float4 pv = *reinterpret_cast<const float4*>(
                &patch_s[cur][(b0 + bi) * 128 + kl * 4]);
            #pragma unroll
            for (int cj = 0; cj < 4; ++cj)
                acc[bi][cj] += pv.x * wv[cj].x + pv.y * wv[cj].y
                             + pv.z * wv[cj].z + pv.w * wv[cj].w;
        }
        if (more) {
            *reinterpret_cast<float4*>(&patch_s[cur ^ 1][tid * 4]) = t0;
            *reinterpret_cast<float4*>(&patch_s[cur ^ 1][2048 + tid * 4]) = t1;
            #pragma unroll
            for (int cj = 0; cj < 4; ++cj) wv[cj] = wvn[cj];
        }
        __syncthreads();
        cur ^= 1;
    }

    #pragma unroll
    for (int bi = 0; bi < 8; ++bi)
        #pragma unroll
        for (int cj = 0; cj < 4; ++cj) {
            float v = acc[bi][cj];
            v += __shfl_xor(v, 1);
            v += __shfl_xor(v, 2);
            v += __shfl_xor(v, 4);
            v += __shfl_xor(v, 8);
            v += __shfl_xor(v, 16);
            acc[bi][cj] = v;
        }

    if (kl == 0) {
        #pragma unroll
        for (int bi = 0; bi < 8; ++bi)
            #pragma unroll
            for (int cj = 0; cj < 4; ++cj)
                part[(size_t)(ks * 32 + b0 + bi) * 4096 + oblk * 16 + cog * 4 + cj] =
                    acc[bi][cj];
    }
}

__global__ __launch_bounds__(256) void fc_reduce_kernel(
    const float* __restrict__ part, const float* __restrict__ bias,
    float* __restrict__ out)
{
    int i4 = blockIdx.x * 256 + threadIdx.x;
    if (i4 >= 32768) return;
    int b = i4 >> 10, o4 = i4 & 1023;
    const size_t stride = (size_t)32 * 4096;
    const float* base = part + (size_t)b * 4096 + o4 * 4;
    float4 s0 = *reinterpret_cast<const float4*>(base);
    float4 s1 = *reinterpret_cast<const float4*>(base + stride);
    float4 s2 = *reinterpret_cast<const float4*>(base + 2 * stride);
    float4 s3 = *reinterpret_cast<const float4*>(base + 3 * stride);
    float4 bv = *reinterpret_cast<const float4*>(bias + o4 * 4);
    float4 r;
    r.x = s0.x + s1.x + s2.x + s3.x + bv.x;
    r.y = s0.y + s1.y + s2.y + s3.y + bv.y;
    r.z = s0.z + s1.z + s2.z + s3.z + bv.z;
    r.w = s0.w + s1.w + s2.w + s3.w + bv.w;
    *reinterpret_cast<float4*>(out + b * 4096 + o4 * 4) = r;
}

// ---------------------------------------------------------------------------
extern "C" void kernel_launch(void* const* d_in, const int* in_sizes, int n_in,
                              void* d_out, int out_size, void* d_ws, size_t ws_size,
                              hipStream_t stream) {
    const float* x    = (const float*)d_in[0];
    const float* c1w  = (const float*)d_in[1];
    const float* c1b  = (const float*)d_in[2];
    const float* c2w  = (const float*)d_in[3];
    const float* c2b  = (const float*)d_in[4];
    const float* lc1w = (const float*)d_in[5];
    const float* lc1b = (const float*)d_in[6];
    const float* lc2w = (const float*)d_in[7];
    const float* lc2b = (const float*)d_in[8];
    const float* lc3w = (const float*)d_in[9];
    const float* lc3b = (const float*)d_in[10];
    const float* fcw  = (const float*)d_in[11];
    const float* fcb  = (const float*)d_in[12];
    float* out = (float*)d_out;

    float* ws  = (float*)d_ws;
    float* h1p = ws;                 // padded: 32*32*71*72 = 5,234,688
    float* h2  = h1p + 5234688;      // padded: 32*16*63*64 = 2,064,384 (+64)
    float* h3  = h2  + 2064448;      // 32*16*55*55 = 1,548,800
    float* h4  = h3  + 1548800;      // 32*16*25*25 =   320,000
    float* h5  = h4  + 320000;       // 32*16*21*21 =   225,792
    unsigned short* w2h = (unsigned short*)(h5 + 225792);  // 41472 ushorts
    unsigned short* w2l = w2h + 41472;                     // 41472 ushorts
    float* lc1_part = h1p;           // 3025*2*3*256 = 4,646,400 floats (<h1p)
    float* fc_part  = h1p;           // sequential reuse for fc

    conv2_wprep_kernel<<<dim3(162), 256, 0, stream>>>(c2w, w2h, w2l);
    conv1_pool_v2_kernel<<<dim3(25, 4, 32), 256, 0, stream>>>(x, c1w, c1b, h1p);
    conv2_mfma_kernel<<<dim3(4, 16, 32), 256, 0, stream>>>(h1p, w2h, w2l, c2b, h2);
    lc1_mfma_kernel<<<dim3(55 * 55 * 6), 512, 0, stream>>>(h2, lc1w, lc1_part);
    lc1_reduce_kernel<<<dim3((55 * 55 * 2 * 256 + 255) / 256), 256, 0, stream>>>(
        lc1_part, lc1b, h3);
    lc_v10_kernel<7, 2, 55, 55, 25, 25><<<dim3(25 * 25), 512, 0, stream>>>(h3, lc2w, lc2b, h4);
    lc_v10_kernel<5, 1, 25, 25, 21, 21><<<dim3(21 * 21), 512, 0, stream>>>(h4, lc3w, lc3b, h5);
    fc_v5_kernel<<<dim3(256, 4), 512, 0, stream>>>(h5, fcw, fc_part);
    fc_reduce_kernel<<<dim3(128), 256, 0, stream>>>(fc_part, fcb, out);
}

// Round 30
// 529.069 us; speedup vs baseline: 1.0967x; 1.0967x over previous
//
#include <hip/hip_runtime.h>

typedef __attribute__((ext_vector_type(8))) short bf16x8;
typedef __attribute__((ext_vector_type(4))) float f32x4;

// Bijective XCD-aware block swizzle (m204 variant; safe for nwg % 8 != 0).
__device__ __forceinline__ int xcd_swizzle(int bid, int nwg) {
    int q = nwg >> 3, r = nwg & 7;
    int xcd = bid & 7, idx = bid >> 3;
    return (xcd < r) ? xcd * (q + 1) + idx
                     : r * (q + 1) + (xcd - r) * q + idx;
}

// split fp32 -> bf16 hi + bf16 lo  (hi = truncated top16; lo = bf16(f - hi))
__device__ __forceinline__ void split_bf16(const float* v, bf16x8& hi, bf16x8& lo) {
    #pragma unroll
    for (int j = 0; j < 8; ++j) {
        unsigned u = __float_as_uint(v[j]);
        unsigned h = u >> 16;
        hi[j] = (short)h;
        float hf = __uint_as_float(h << 16);
        float lf = v[j] - hf;
        lo[j] = (short)(__float_as_uint(lf) >> 16);
    }
}

// ---------------------------------------------------------------------------
// Stage 1 v2b: conv1 (11x11) + ReLU + maxpool. Output row stride 72 (padded).
// ---------------------------------------------------------------------------
__global__ __launch_bounds__(256, 4) void conv1_pool_v2_kernel(
    const float* __restrict__ x, const float* __restrict__ w,
    const float* __restrict__ bias, float* __restrict__ out)
{
    const int tile = blockIdx.x;          // 0..24
    const int cog  = blockIdx.y;          // 0..3  (8 couts each)
    const int b    = blockIdx.z;          // 0..31
    const int ty = tile / 5, tx = tile % 5;
    const int pr0 = ty * 16, pc0 = tx * 16;
    const int cr0 = pr0 * 2, cc0 = pc0 * 2;

    __shared__ float in_s[43 * 44];
    __shared__ float w_s[8][121];
    __shared__ float hp_s[33][8][17];

    const int tid = threadIdx.x;

    const float* xb = x + b * 152 * 152;
    for (int i = tid; i < 43 * 44; i += 256) {
        int r = i / 44, c = i - r * 44;
        int ir = cr0 + r, ic = cc0 + c;
        in_s[i] = (ir < 152 && ic < 152) ? xb[ir * 152 + ic] : 0.f;
    }
    for (int i = tid; i < 8 * 121; i += 256) {
        int co = i / 121, k = i - co * 121;
        w_s[co][k] = w[(cog * 8 + co) * 121 + k];
    }
    __syncthreads();

    for (int task = tid; task < 264; task += 256) {
        const int co  = task & 7;
        const int row = task >> 3;
        float hmax[16];
        if (cr0 + row < 142) {
            float acc[33];
            #pragma unroll
            for (int px = 0; px < 33; ++px) acc[px] = 0.f;
            #pragma unroll 1
            for (int kh = 0; kh < 11; ++kh) {
                float4 rq[11];
                #pragma unroll
                for (int j = 0; j < 11; ++j)
                    rq[j] = *reinterpret_cast<const float4*>(
                        &in_s[(row + kh) * 44 + j * 4]);
                const float* rr = reinterpret_cast<const float*>(rq);
                #pragma unroll
                for (int kw = 0; kw < 11; ++kw) {
                    float wv = w_s[co][kh * 11 + kw];
                    #pragma unroll
                    for (int px = 0; px < 33; ++px)
                        acc[px] += rr[px + kw] * wv;
                }
            }
            const float bv = bias[cog * 8 + co];
            #pragma unroll
            for (int px = 0; px < 33; ++px) {
                float v = fmaxf(acc[px] + bv, 0.f);
                acc[px] = (cc0 + px < 142) ? v : 0.f;
            }
            #pragma unroll
            for (int pc = 0; pc < 16; ++pc)
                hmax[pc] = fmaxf(fmaxf(acc[2 * pc], acc[2 * pc + 1]), acc[2 * pc + 2]);
        } else {
            #pragma unroll
            for (int pc = 0; pc < 16; ++pc) hmax[pc] = 0.f;
        }
        #pragma unroll
        for (int pc = 0; pc < 16; ++pc) hp_s[row][co][pc] = hmax[pc];
    }
    __syncthreads();

    for (int t = tid; t < 2048; t += 256) {
        int co = t >> 8, r = t & 255;
        int ppy = r >> 4, ppc = r & 15;
        float v = fmaxf(fmaxf(hp_s[2 * ppy][co][ppc], hp_s[2 * ppy + 1][co][ppc]),
                        hp_s[2 * ppy + 2][co][ppc]);
        int pr = pr0 + ppy, pc = pc0 + ppc;
        if (pr < 71 && pc < 71)
            out[((b * 32 + cog * 8 + co) * 71 + pr) * 72 + pc] = v;
    }
}

// ---------------------------------------------------------------------------
// conv2 weight prepass: fp32 [16co][32ci][9][9] -> bf16 hi/lo in
// k-order (khkw, ci): dst[khkw*512 + co*32 + ci].
// ---------------------------------------------------------------------------
__global__ __launch_bounds__(256) void conv2_wprep_kernel(
    const float* __restrict__ w, unsigned short* __restrict__ wh,
    unsigned short* __restrict__ wl)
{
    int i = blockIdx.x * 256 + threadIdx.x;
    if (i >= 41472) return;
    int ci = i & 31, co = (i >> 5) & 15, khkw = i >> 9;
    float v = w[(co * 32 + ci) * 81 + khkw];
    unsigned u = __float_as_uint(v);
    unsigned h = u >> 16;
    wh[i] = (unsigned short)h;
    float lf = v - __uint_as_float(h << 16);
    wl[i] = (unsigned short)(__float_as_uint(lf) >> 16);
}

// ---------------------------------------------------------------------------
// Stage 2 v6 (MFMA): conv2 + ReLU, bf16x3.
// ---------------------------------------------------------------------------
__global__ __launch_bounds__(256) void conv2_mfma_kernel(
    const float* __restrict__ in, const unsigned short* __restrict__ wh,
    const unsigned short* __restrict__ wl, const float* __restrict__ bias,
    float* __restrict__ out)
{
    __shared__ unsigned short inh[12 * 24 * 32];
    __shared__ unsigned short inl[12 * 24 * 32];

    const int owt = blockIdx.x;            // 0..3
    const int ohg = blockIdx.y;            // 0..15
    const int b   = blockIdx.z;            // 0..31
    const int ow0 = owt * 16, r0 = ohg * 4;
    const int tid = threadIdx.x;

    for (int t = tid; t < 384; t += 256) {
        int r = t >> 5, ci = t & 31;
        int ih = r0 + r;
        const bool rowok = (ih < 71);
        const float* src = in + ((size_t)(b * 32 + ci) * 71 + ih) * 72 + ow0;
        float4 f[6];
        #pragma unroll
        for (int c4 = 0; c4 < 6; ++c4)
            f[c4] = *reinterpret_cast<const float4*>(src + c4 * 4);  // safe: ws
        const float* vals = reinterpret_cast<const float*>(f);
        unsigned short* ph = &inh[(r * 24) * 32 + ci];
        unsigned short* pl = &inl[(r * 24) * 32 + ci];
        #pragma unroll
        for (int c = 0; c < 24; ++c) {
            float v = (rowok && (ow0 + c) < 71) ? vals[c] : 0.f;
            unsigned u = __float_as_uint(v);
            unsigned h = u >> 16;
            ph[c * 32] = (unsigned short)h;
            float lf = v - __uint_as_float(h << 16);
            pl[c * 32] = (unsigned short)(__float_as_uint(lf) >> 16);
        }
    }
    __syncthreads();

    const int wid  = tid >> 6;
    const int lane = tid & 63;
    const int q15  = lane & 15;
    const int kq   = lane >> 4;
    const int oh   = r0 + wid;

    f32x4 acc = {0.f, 0.f, 0.f, 0.f};

    #pragma unroll 1
    for (int kh = 0; kh < 9; ++kh) {
        #pragma unroll
        for (int kw = 0; kw < 9; ++kw) {
            const int s = kh * 9 + kw;
            const int abase = ((wid + kh) * 24 + (q15 + kw)) * 32 + kq * 8;
            bf16x8 ah = *reinterpret_cast<const bf16x8*>(&inh[abase]);
            bf16x8 al = *reinterpret_cast<const bf16x8*>(&inl[abase]);
            const int bbase = (s * 16 + q15) * 32 + kq * 8;
            bf16x8 bh = *reinterpret_cast<const bf16x8*>(&wh[bbase]);
            bf16x8 bl = *reinterpret_cast<const bf16x8*>(&wl[bbase]);
            acc = __builtin_amdgcn_mfma_f32_16x16x32_bf16(ah, bh, acc, 0, 0, 0);
            acc = __builtin_amdgcn_mfma_f32_16x16x32_bf16(ah, bl, acc, 0, 0, 0);
            acc = __builtin_amdgcn_mfma_f32_16x16x32_bf16(al, bh, acc, 0, 0, 0);
        }
    }

    if (oh < 63) {
        const int co = q15;
        const int pw = kq * 4;
        const float bv = bias[co];
        float r4[4];
        #pragma unroll
        for (int j = 0; j < 4; ++j) r4[j] = fmaxf(acc[j] + bv, 0.f);
        float* dst = &out[((size_t)(b * 16 + co) * 63 + oh) * 64 + ow0 + pw];
        if (ow0 + pw + 3 < 63) {
            *reinterpret_cast<float4*>(dst) = make_float4(r4[0], r4[1], r4[2], r4[3]);
        } else {
            #pragma unroll
            for (int j = 0; j < 4; ++j)
                if (ow0 + pw + j < 63) dst[j] = r4[j];
        }
    }
}

// ---------------------------------------------------------------------------
// Stage 3 (lc1) v18: MFMA bf16x3, 3-way split-K across blocks. (172us
// plateau; residual is unhideable per-position weight-stream latency.)
// ---------------------------------------------------------------------------
__global__ __launch_bounds__(512) void lc1_mfma_kernel(
    const float* __restrict__ in, const float* __restrict__ w,
    float* __restrict__ part)
{
    constexpr int K     = 1296;
    constexpr int WPAD  = 64;
    constexpr int PLANE = 63 * WPAD;       // 4032
    constexpr int CHW   = 16 * PLANE;      // 64512
    constexpr int HW    = 55 * 55;
    constexpr int SPAN  = 452;             // 452%32=4 -> bank-rotated rows

    __shared__ float patch_f[16 * SPAN];   // 28,928 B
    __shared__ float red[8 * 256];         //  8,192 B

    const int tid = threadIdx.x;
    const int sb = xcd_swizzle(blockIdx.x, 6 * HW);
    const int pos  = sb / 6;
    const int rem  = sb - pos * 6;
    const int halfv = rem / 3;
    const int ks    = rem - halfv * 3;
    const int sbeg = (ks == 0) ? 0 : (ks == 1) ? 14 : 28;
    const int send = (ks == 0) ? 14 : (ks == 1) ? 28 : 41;
    const int klo  = sbeg * 32;            // 0 / 448 / 896
    const int spanUsed = send * 32 - klo;  // 448 / 448 / 416
    const int rbeg = klo / 9;              // 0 / 49 / 99
    const int rend = min((send * 32 - 1) / 9, 143);
    const int nrows = rend - rbeg + 1;

    const int oh = pos / 55, ow = pos % 55;
    const int sh = ow & 3;
    const int gbase = oh * WPAD + (ow - sh);

    if (ks == 2) {
        for (int i = tid; i < 16 * 16; i += 512)
            patch_f[(i >> 4) * SPAN + 400 + (i & 15)] = 0.f;
    }

    const float* inb = in + halfv * 16 * CHW;
    for (int t = tid; t < 16 * nrows; t += 512) {
        const int b    = t & 15;
        const int rest = rbeg + (t >> 4);
        const float* src = inb + b * CHW + (rest / 9) * PLANE
                         + gbase + (rest - (rest / 9) * 9) * WPAD;
        float4 f0 = *reinterpret_cast<const float4*>(src);
        float4 f1 = *reinterpret_cast<const float4*>(src + 4);
        float4 f2 = *reinterpret_cast<const float4*>(src + 8);
        float vals[12];
        *reinterpret_cast<float4*>(&vals[0]) = f0;
        *reinterpret_cast<float4*>(&vals[4]) = f1;
        *reinterpret_cast<float4*>(&vals[8]) = f2;
        float* p = &patch_f[b * SPAN];
        const int kbase = rest * 9;
        #pragma unroll
        for (int j = 0; j < 9; ++j) {
            const int local = kbase + j - klo;
            if (local >= 0 && local < spanUsed)
                p[local] = vals[sh + j];
        }
    }
    __syncthreads();

    const int wid  = tid >> 6;             // wave 0..7
    const int lane = tid & 63;
    const int bq = lane & 15;
    const int kq = lane >> 4;

    f32x4 acc = {0.f, 0.f, 0.f, 0.f};
    const float* wpos = w + (size_t)pos * 16 * K + (size_t)bq * K;

    auto loadA = [&](int s, float* av) {
        const float* ap = &patch_f[bq * SPAN + (s * 32 - klo) + kq * 8];
        *reinterpret_cast<float4*>(&av[0]) = *reinterpret_cast<const float4*>(ap);
        *reinterpret_cast<float4*>(&av[4]) = *reinterpret_cast<const float4*>(ap + 4);
    };
    auto loadB = [&](int s, float* wv) {
        const int k8 = s * 32 + kq * 8;
        if (k8 < K) {
            *reinterpret_cast<float4*>(&wv[0]) =
                *reinterpret_cast<const float4*>(wpos + k8);
            *reinterpret_cast<float4*>(&wv[4]) =
                *reinterpret_cast<const float4*>(wpos + k8 + 4);
        } else {
            #pragma unroll
            for (int j = 0; j < 8; ++j) wv[j] = 0.f;
        }
    };

    int s = sbeg + wid;
    if (s < send) {
        float av[8], wv[8], avn[8], wvn[8];
        loadB(s, wv);
        loadA(s, av);
        #pragma unroll 1
        while (true) {
            const int sn = s + 8;
            const bool more = (sn < send);
            if (more) { loadB(sn, wvn); loadA(sn, avn); }
            bf16x8 ah, al, bh, bl;
            split_bf16(av, ah, al);
            split_bf16(wv, bh, bl);
            acc = __builtin_amdgcn_mfma_f32_16x16x32_bf16(ah, bh, acc, 0, 0, 0);
            acc = __builtin_amdgcn_mfma_f32_16x16x32_bf16(ah, bl, acc, 0, 0, 0);
            acc = __builtin_amdgcn_mfma_f32_16x16x32_bf16(al, bh, acc, 0, 0, 0);
            if (!more) break;
            #pragma unroll
            for (int j = 0; j < 8; ++j) { av[j] = avn[j]; wv[j] = wvn[j]; }
            s = sn;
        }
    }

    *reinterpret_cast<float4*>(&red[(wid * 64 + lane) * 4]) =
        make_float4(acc[0], acc[1], acc[2], acc[3]);
    __syncthreads();

    if (tid < 256) {
        float s2 = 0.f;
        #pragma unroll
        for (int wv2 = 0; wv2 < 8; ++wv2)
            s2 += red[wv2 * 256 + tid];
        part[((size_t)(pos * 2 + halfv) * 3 + ks) * 256 + tid] = s2;
    }
}

// lc1 split-K reduce: sum 3 ksplits + bias + relu -> h3.
__global__ __launch_bounds__(256) void lc1_reduce_kernel(
    const float* __restrict__ part, const float* __restrict__ bias,
    float* __restrict__ out)
{
    constexpr int HW = 55 * 55;
    int idx = blockIdx.x * 256 + threadIdx.x;
    if (idx >= HW * 2 * 256) return;
    int base = idx >> 8;
    int t    = idx & 255;
    float v = part[((size_t)base * 3 + 0) * 256 + t]
            + part[((size_t)base * 3 + 1) * 256 + t]
            + part[((size_t)base * 3 + 2) * 256 + t];
    int pos = base >> 1, half = base & 1;
    int lane = t >> 2, reg = t & 3;
    int row = ((lane >> 4) << 2) + reg;
    int col = lane & 15;
    int b = half * 16 + row;
    out[(b * 16 + col) * HW + pos] = fmaxf(v + bias[col * HW + pos], 0.f);
}

// ---------------------------------------------------------------------------
// Stages 4-5 (lc2, lc3) v10: proven template, unchanged.
// ---------------------------------------------------------------------------
template<int KS, int STRIDE, int HIN, int WIN, int HOUT, int WOUT>
__global__ __launch_bounds__(512) void lc_v10_kernel(
    const float* __restrict__ in, const float* __restrict__ w,
    const float* __restrict__ bias, float* __restrict__ out)
{
    constexpr int K     = 16 * KS * KS;
    constexpr int K2    = KS * KS;
    constexpr int NPASS = (K + 127) / 128;
    constexpr int KPAD  = NPASS * 128;
    constexpr int HW    = HOUT * WOUT;
    constexpr int CHW   = 16 * HIN * WIN;

    __shared__ float patch_s[2][4096];
    __shared__ int   base_s[KPAD];

    const int tid = threadIdx.x;
    const int pos = xcd_swizzle(blockIdx.x, HW);
    const int oh = pos / WOUT, ow = pos % WOUT;
    const int posoff = (oh * STRIDE) * WIN + ow * STRIDE;

    for (int k = tid; k < KPAD; k += 512) {
        int v = 0;
        if (k < K) {
            int ci = k / K2;
            int r  = k - ci * K2;
            int kh = r / KS, kw = r - kh * KS;
            v = ci * (HIN * WIN) + kh * WIN + kw;
        }
        base_s[k] = v;
    }

    const int kl  = tid & 31;
    const int cog = (tid >> 5) & 3;
    const int bg  = tid >> 7;
    const int b0  = bg * 8;

    const int sb = tid >> 5;
    const int k0 = (tid & 31) * 4;
    const float* gsrc0 = in + sb * CHW + posoff;
    const float* gsrc1 = gsrc0 + 16 * CHW;

    const float* wbase = w + (size_t)pos * 16 * K;

    float acc[8][4];
    #pragma unroll
    for (int i = 0; i < 8; ++i)
        #pragma unroll
        for (int j = 0; j < 4; ++j) acc[i][j] = 0.f;

    __syncthreads();

    {
        int4 off4 = *reinterpret_cast<const int4*>(&base_s[k0]);
        float t0x = gsrc0[off4.x], t0y = gsrc0[off4.y],
              t0z = gsrc0[off4.z], t0w = gsrc0[off4.w];
        float t1x = gsrc1[off4.x], t1y = gsrc1[off4.y],
              t1z = gsrc1[off4.z], t1w = gsrc1[off4.w];
        *reinterpret_cast<float4*>(&patch_s[0][tid * 4]) =
            make_float4(t0x, t0y, t0z, t0w);
        *reinterpret_cast<float4*>(&patch_s[0][2048 + tid * 4]) =
            make_float4(t1x, t1y, t1z, t1w);
    }
    asm volatile("s_waitcnt lgkmcnt(0)" ::: "memory");
    __builtin_amdgcn_s_barrier();

    int cur = 0;
    #pragma unroll 1
    for (int ps = 0; ps < NPASS; ++ps) {
        const bool more = (ps + 1 < NPASS);
        float4 wv[4];
        {
            const int kw4 = ps * 128 + kl * 4;
            #pragma unroll
            for (int cj = 0; cj < 4; ++cj)
                wv[cj] = (kw4 < K)
                    ? *reinterpret_cast<const float4*>(wbase + (size_t)(cog * 4 + cj) * K + kw4)
                    : make_float4(0.f, 0.f, 0.f, 0.f);
        }
        float t0x, t0y, t0z, t0w, t1x, t1y, t1z, t1w;
        if (more) {
            int4 off4 = *reinterpret_cast<const int4*>(&base_s[(ps + 1) * 128 + k0]);
            t0x = gsrc0[off4.x]; t0y = gsrc0[off4.y];
            t0z = gsrc0[off4.z]; t0w = gsrc0[off4.w];
            t1x = gsrc1[off4.x]; t1y = gsrc1[off4.y];
            t1z = gsrc1[off4.z]; t1w = gsrc1[off4.w];
        }
        #pragma unroll
        for (int bi = 0; bi < 8; ++bi) {
            float4 pv = *reinterpret_cast<const float4*>(
                &patch_s[cur][(b0 + bi) * 128 + kl * 4]);
            #pragma unroll
            for (int cj = 0; cj < 4; ++cj)
                acc[bi][cj] += pv.x * wv[cj].x + pv.y * wv[cj].y
                             + pv.z * wv[cj].z + pv.w * wv[cj].w;
        }
        if (more) {
            *reinterpret_cast<float4*>(&patch_s[cur ^ 1][tid * 4]) =
                make_float4(t0x, t0y, t0z, t0w);
            *reinterpret_cast<float4*>(&patch_s[cur ^ 1][2048 + tid * 4]) =
                make_float4(t1x, t1y, t1z, t1w);
        }
        asm volatile("s_waitcnt lgkmcnt(0)" ::: "memory");
        __builtin_amdgcn_s_barrier();
        cur ^= 1;
    }

    #pragma unroll
    for (int bi = 0; bi < 8; ++bi)
        #pragma unroll
        for (int cj = 0; cj < 4; ++cj) {
            float v = acc[bi][cj];
            v += __shfl_xor(v, 1);
            v += __shfl_xor(v, 2);
            v += __shfl_xor(v, 4);
            v += __shfl_xor(v, 8);
            v += __shfl_xor(v, 16);
            acc[bi][cj] = v;
        }

    if (kl == 0) {
        float bv[4];
        #pragma unroll
        for (int cj = 0; cj < 4; ++cj)
            bv[cj] = bias[(cog * 4 + cj) * HW + pos];
        #pragma unroll
        for (int bi = 0; bi < 8; ++bi)
            #pragma unroll
            for (int cj = 0; cj < 4; ++cj) {
                int b = b0 + bi, co = cog * 4 + cj;
                out[(b * 16 + co) * HW + pos] = fmaxf(acc[bi][cj] + bv[cj], 0.f);
            }
    }
}

// ---------------------------------------------------------------------------
// Stage 6 v5: FC (32,7056)@(4096,7056)^T, 4-way split-K (proven r25 config).
// ---------------------------------------------------------------------------
__global__ __launch_bounds__(512) void fc_v5_kernel(
    const float* __restrict__ in, const float* __restrict__ w,
    float* __restrict__ part)
{
    constexpr int K = 7056, KR = 1764;
    constexpr int NPASS = (KR + 127) / 128;   // 14

    __shared__ float patch_s[2][4096];

    const int tid  = threadIdx.x;
    const int oblk = blockIdx.x;
    const int ks   = blockIdx.y;
    const int kbeg = ks * KR, klim = kbeg + KR;

    const int kl  = tid & 31;
    const int cog = (tid >> 5) & 3;
    const int bg  = tid >> 7;
    const int b0  = bg * 8;

    const int sb = tid >> 5;
    const int k0 = (tid & 31) * 4;
    const float* row0 = in + sb * K;
    const float* row1 = row0 + 16 * K;

    const float* wbase = w + (size_t)(oblk * 16) * K;

    auto ld4 = [&](const float* row, int kg) -> float4 {
        return (kg < klim) ? *reinterpret_cast<const float4*>(row + kg)
                           : make_float4(0.f, 0.f, 0.f, 0.f);
    };

    float acc[8][4];
    #pragma unroll
    for (int i = 0; i < 8; ++i)
        #pragma unroll
        for (int j = 0; j < 4; ++j) acc[i][j] = 0.f;

    float4 wv[4], wvn[4];
    float4 t0, t1;

    {
        const int kw4 = kbeg + kl * 4;
        #pragma unroll
        for (int cj = 0; cj < 4; ++cj)
            wv[cj] = (kw4 < klim)
                ? *reinterpret_cast<const float4*>(wbase + (size_t)(cog * 4 + cj) * K + kw4)
                : make_float4(0.f, 0.f, 0.f, 0.f);
        t0 = ld4(row0, kbeg + k0);
        t1 = ld4(row1, kbeg + k0);
        *reinterpret_cast<float4*>(&patch_s[0][tid * 4]) = t0;
        *reinterpret_cast<float4*>(&patch_s[0][2048 + tid * 4]) = t1;
    }
    __syncthreads();

    int cur = 0;
    #pragma unroll 1
    for (int ps = 0; ps < NPASS; ++ps) {
        const bool more = (ps + 1 < NPASS);
        if (more) {
            const int kbn = kbeg + (ps + 1) * 128;
            t0 = ld4(row0, kbn + k0);
            t1 = ld4(row1, kbn + k0);
            const int kw4n = kbn + kl * 4;
            #pragma unroll
            for (int cj = 0; cj < 4; ++cj)
                wvn[cj] = (kw4n < klim)
                    ? *reinterpret_cast<const float4*>(wbase + (size_t)(cog * 4 + cj) * K + kw4n)
                    : make_float4(0.f, 0.f, 0.f, 0.f);
        }
        #pragma unroll
        for (int bi = 0; bi < 8; ++bi) {
            float4 pv = *reinterpret_cast<const float4*>(
                &patch_s[cur][(b0 + bi) * 128 + kl * 4]);
            #pragma unroll
            for (int cj = 0; cj < 4; ++cj)
                acc[bi][cj] += pv.x * wv[cj].x + pv.y * wv[cj].y
                             + pv.z * wv[cj].z + pv.w * wv[cj].w;
        }
        if (more) {
            *reinterpret_cast<float4*>(&patch_s[cur ^ 1][tid * 4]) = t0;
            *reinterpret_cast<float4*>(&patch_s[cur ^ 1][2048 + tid * 4]) = t1;
            #pragma unroll
            for (int cj = 0; cj < 4; ++cj) wv[cj] = wvn[cj];
        }
        __syncthreads();
        cur ^= 1;
    }

    #pragma unroll
    for (int bi = 0; bi < 8; ++bi)
        #pragma unroll
        for (int cj = 0; cj < 4; ++cj) {
            float v = acc[bi][cj];
            v += __shfl_xor(v, 1);
            v += __shfl_xor(v, 2);
            v += __shfl_xor(v, 4);
            v += __shfl_xor(v, 8);
            v += __shfl_xor(v, 16);
            acc[bi][cj] = v;
        }

    if (kl == 0) {
        #pragma unroll
        for (int bi = 0; bi < 8; ++bi)
            #pragma unroll
            for (int cj = 0; cj < 4; ++cj)
                part[(size_t)(ks * 32 + b0 + bi) * 4096 + oblk * 16 + cog * 4 + cj] =
                    acc[bi][cj];
    }
}

__global__ __launch_bounds__(256) void fc_reduce_kernel(
    const float* __restrict__ part, const float* __restrict__ bias,
    float* __restrict__ out)
{
    int i4 = blockIdx.x * 256 + threadIdx.x;
    if (i4 >= 32768) return;
    int b = i4 >> 10, o4 = i4 & 1023;
    const size_t stride = (size_t)32 * 4096;
    const float* base = part + (size_t)b * 4096 + o4 * 4;
    float4 s0 = *reinterpret_cast<const float4*>(base);
    float4 s1 = *reinterpret_cast<const float4*>(base + stride);
    float4 s2 = *reinterpret_cast<const float4*>(base + 2 * stride);
    float4 s3 = *reinterpret_cast<const float4*>(base + 3 * stride);
    float4 bv = *reinterpret_cast<const float4*>(bias + o4 * 4);
    float4 r;
    r.x = s0.x + s1.x + s2.x + s3.x + bv.x;
    r.y = s0.y + s1.y + s2.y + s3.y + bv.y;
    r.z = s0.z + s1.z + s2.z + s3.z + bv.z;
    r.w = s0.w + s1.w + s2.w + s3.w + bv.w;
    *reinterpret_cast<float4*>(out + b * 4096 + o4 * 4) = r;
}

// ---------------------------------------------------------------------------
extern "C" void kernel_launch(void* const* d_in, const int* in_sizes, int n_in,
                              void* d_out, int out_size, void* d_ws, size_t ws_size,
                              hipStream_t stream) {
    const float* x    = (const float*)d_in[0];
    const float* c1w  = (const float*)d_in[1];
    const float* c1b  = (const float*)d_in[2];
    const float* c2w  = (const float*)d_in[3];
    const float* c2b  = (const float*)d_in[4];
    const float* lc1w = (const float*)d_in[5];
    const float* lc1b = (const float*)d_in[6];
    const float* lc2w = (const float*)d_in[7];
    const float* lc2b = (const float*)d_in[8];
    const float* lc3w = (const float*)d_in[9];
    const float* lc3b = (const float*)d_in[10];
    const float* fcw  = (const float*)d_in[11];
    const float* fcb  = (const float*)d_in[12];
    float* out = (float*)d_out;

    float* ws  = (float*)d_ws;
    float* h1p = ws;                 // padded: 32*32*71*72 = 5,234,688
    float* h2  = h1p + 5234688;      // padded: 32*16*63*64 = 2,064,384 (+64)
    float* h3  = h2  + 2064448;      // 32*16*55*55 = 1,548,800
    float* h4  = h3  + 1548800;      // 32*16*25*25 =   320,000
    float* h5  = h4  + 320000;       // 32*16*21*21 =   225,792
    unsigned short* w2h = (unsigned short*)(h5 + 225792);  // 41472 ushorts
    unsigned short* w2l = w2h + 41472;                     // 41472 ushorts
    float* lc1_part = h1p;           // 3025*2*3*256 = 4,646,400 floats (<h1p)
    float* fc_part  = h1p;           // sequential reuse for fc

    conv2_wprep_kernel<<<dim3(162), 256, 0, stream>>>(c2w, w2h, w2l);
    conv1_pool_v2_kernel<<<dim3(25, 4, 32), 256, 0, stream>>>(x, c1w, c1b, h1p);
    conv2_mfma_kernel<<<dim3(4, 16, 32), 256, 0, stream>>>(h1p, w2h, w2l, c2b, h2);
    lc1_mfma_kernel<<<dim3(55 * 55 * 6), 512, 0, stream>>>(h2, lc1w, lc1_part);
    lc1_reduce_kernel<<<dim3((55 * 55 * 2 * 256 + 255) / 256), 256, 0, stream>>>(
        lc1_part, lc1b, h3);
    lc_v10_kernel<7, 2, 55, 55, 25, 25><<<dim3(25 * 25), 512, 0, stream>>>(h3, lc2w, lc2b, h4);
    lc_v10_kernel<5, 1, 25, 25, 21, 21><<<dim3(21 * 21), 512, 0, stream>>>(h4, lc3w, lc3b, h5);
    fc_v5_kernel<<<dim3(256, 4), 512, 0, stream>>>(h5, fcw, fc_part);
    fc_reduce_kernel<<<dim3(128), 256, 0, stream>>>(fc_part, fcb, out);
}